// Round 1
// baseline (208.599 us; speedup 1.0000x reference)
//
#include <hip/hip_runtime.h>

// FrequencyConv: out[b,o,h,w] = sum_i x[b,i,h,w] * Khat[o,i,h,w]
// Khat[o,i,h,w] = sum_{p,q<3} (wr + i*wi)[o,i,p,q] * exp(-2*pi*i*(h*p + w*q)/256)
// Output: (2, B, COUT, H, W) = (real, imag) stacked, fp32.

constexpr int Hd   = 256;
constexpr int Wd   = 256;
constexpr int Bn   = 16;
constexpr int CIN  = 16;
constexpr int COUT = 16;
constexpr int TW   = 32;   // w-positions per block (one full 128B line per (b,i) row)
constexpr int NTHREADS = 512;  // 16 o * 32 p

__global__ __launch_bounds__(NTHREADS)
void freq_conv_kernel(const float* __restrict__ x,
                      const float* __restrict__ wr_g,
                      const float* __restrict__ wi_g,
                      float* __restrict__ out)
{
    __shared__ float xs[Bn * CIN * TW]; // [b][i][p], 32 KB

    const int tid = threadIdx.x;
    const int bid = blockIdx.x;
    const int h  = bid >> 3;           // 256 rows
    const int w0 = (bid & 7) * TW;

    // ---- issue x staging loads early (hide latency under Khat compute) ----
    float4 stage[4];
#pragma unroll
    for (int t = 0; t < 4; ++t) {
        int lin = t * NTHREADS + tid;          // 0..2047 float4s
        int row = lin >> 3;                    // (b*16 + i), 0..255
        int seg = lin & 7;                     // float4 within 32-float row
        stage[t] = *reinterpret_cast<const float4*>(
            &x[(size_t)(row * Hd + h) * Wd + w0 + seg * 4]);
    }

    const int o = tid >> 5;   // 0..15
    const int p = tid & 31;   // 0..31
    const int w = w0 + p;

    // ---- phases e^{-i*2pi*(h*pp + w*qq)/256} = cph - i*sph, pp,qq in 0..2 ----
    const float TWO_PI_OVER_N = 6.28318530717958647692f / 256.0f;
    float sh1, ch1, sw1, cw1;
    __sincosf(TWO_PI_OVER_N * (float)h, &sh1, &ch1);
    __sincosf(TWO_PI_OVER_N * (float)w, &sw1, &cw1);
    const float ch[3] = {1.f, ch1, ch1 * ch1 - sh1 * sh1};
    const float sh[3] = {0.f, sh1, 2.f * sh1 * ch1};
    const float cw[3] = {1.f, cw1, cw1 * cw1 - sw1 * sw1};
    const float sw[3] = {0.f, sw1, 2.f * sw1 * cw1};

    float cph[9], sph[9];
#pragma unroll
    for (int pp = 0; pp < 3; ++pp)
#pragma unroll
        for (int qq = 0; qq < 3; ++qq) {
            cph[pp * 3 + qq] = ch[pp] * cw[qq] - sh[pp] * sw[qq];
            sph[pp * 3 + qq] = sh[pp] * cw[qq] + ch[pp] * sw[qq];
        }

    // ---- Khat[o][i] for this thread's (o, w): shared across all 16 batches ----
    float Kr[CIN], Ki[CIN];
#pragma unroll
    for (int i = 0; i < CIN; ++i) {
        float kr = 0.f, ki = 0.f;
        const float* wr = &wr_g[(o * CIN + i) * 9];
        const float* wi = &wi_g[(o * CIN + i) * 9];
#pragma unroll
        for (int t = 0; t < 9; ++t) {
            const float a = wr[t], bb = wi[t];
            kr += a * cph[t] + bb * sph[t];   // Re{(a+ib)(c-is)} = a*c + b*s
            ki += bb * cph[t] - a * sph[t];   // Im = b*c - a*s
        }
        Kr[i] = kr; Ki[i] = ki;
    }

    // ---- commit staged x to LDS ----
#pragma unroll
    for (int t = 0; t < 4; ++t) {
        int lin = t * NTHREADS + tid;
        reinterpret_cast<float4*>(xs)[lin] = stage[t];
    }
    __syncthreads();

    // ---- per-batch contraction over Cin + coalesced stores ----
    const size_t hw = (size_t)h * Wd + w;
#pragma unroll
    for (int b = 0; b < Bn; ++b) {
        float ar = 0.f, ai = 0.f;
#pragma unroll
        for (int i = 0; i < CIN; ++i) {
            const float xv = xs[(b * CIN + i) * TW + p]; // conflict-free + o-broadcast
            ar += xv * Kr[i];
            ai += xv * Ki[i];
        }
        out[((size_t)(b * COUT + o)) * (Hd * Wd) + hw]        = ar; // real part
        out[((size_t)((Bn + b) * COUT + o)) * (Hd * Wd) + hw] = ai; // imag part
    }
}

extern "C" void kernel_launch(void* const* d_in, const int* in_sizes, int n_in,
                              void* d_out, int out_size, void* d_ws, size_t ws_size,
                              hipStream_t stream) {
    const float* x  = (const float*)d_in[0];
    const float* wr = (const float*)d_in[1];
    const float* wi = (const float*)d_in[2];
    float* out = (float*)d_out;

    dim3 grid(Hd * (Wd / TW));   // 256 * 8 = 2048 blocks
    dim3 block(NTHREADS);
    freq_conv_kernel<<<grid, block, 0, stream>>>(x, wr, wi, out);
}